// Round 6
// baseline (653.328 us; speedup 1.0000x reference)
//
#include <hip/hip_runtime.h>

typedef unsigned short u16;
typedef unsigned int u32;
typedef __attribute__((ext_vector_type(8))) short short8;
typedef __attribute__((ext_vector_type(4))) float f32x4;
typedef __attribute__((ext_vector_type(2))) unsigned int u32x2;
typedef __attribute__((ext_vector_type(4))) unsigned int u32x4;

__device__ __forceinline__ u16 f2bf(float f) {
  u32 u = __float_as_uint(f);
  u += 0x7FFFu + ((u >> 16) & 1u);
  return (u16)(u >> 16);
}

// Pure-polynomial exact-GELU for |x| <= 1.5 (error < 3e-6 there).
__device__ __forceinline__ float gelu_poly(float x) {
  const float v = x * x;
  float p = __builtin_fmaf(-4.12267e-8f, v, 6.65969e-7f);
  p = __builtin_fmaf(p, v, -9.44466e-6f);
  p = __builtin_fmaf(p, v, 1.15437e-4f);
  p = __builtin_fmaf(p, v, -1.1873282e-3f);
  p = __builtin_fmaf(p, v, 9.973557e-3f);
  p = __builtin_fmaf(p, v, -6.649038e-2f);
  p = __builtin_fmaf(p, v, 0.3989422804f);
  return x * __builtin_fmaf(x, p, 0.5f);
}

// Fallback for rare |x| > 1.5: A&S 7.1.26 erfc (|err|~1.5e-7), branch-free.
__device__ __forceinline__ float gelu_as(float x) {
  float ax = __builtin_fabsf(0.70710678118654752f * x);
  float t  = __builtin_amdgcn_rcpf(__builtin_fmaf(0.3275911f, ax, 1.0f));
  float p  = __builtin_fmaf(__builtin_fmaf(__builtin_fmaf(__builtin_fmaf(
               0.5307027145f, t, -0.7265760135f), t, 0.7107068705f), t,
               -0.142248368f), t, 0.127414796f);
  float e  = __expf(-(ax * ax));
  float h  = (p * t) * e;
  float phi = (x >= 0.0f) ? (1.0f - h) : h;
  return x * phi;
}

// swizzled byte offset inside a [rows][128 bf16] (256B-stride) LDS tile
__device__ __forceinline__ int swz(int row, int inrow_byte) {
  return (row * 256 + inrow_byte) ^ ((row & 7) << 4);
}

// ---- prep: weights -> bf16 transposed [n][k] in ws (plain layout; B-frags
// read directly from global). ws (u16): [0,65536): layers 1..4 at
// L*16384 + n*128 + k (W1 k-padded 48->128); [65536,67584): W5T n*128+k.
__global__ void prep_weights(const float* __restrict__ W1, const float* __restrict__ W2,
                             const float* __restrict__ W3, const float* __restrict__ W4,
                             const float* __restrict__ W5, u16* __restrict__ ws) {
  int idx = blockIdx.x * 256 + threadIdx.x;
  if (idx < 65536) {
    int L = idx >> 14, rem = idx & 16383;
    int n = rem >> 7, k = rem & 127;
    float v;
    if (L == 0)      v = (k < 48) ? W1[k * 128 + n] : 0.f;
    else if (L == 1) v = W2[k * 128 + n];
    else if (L == 2) v = W3[k * 128 + n];
    else             v = W4[k * 128 + n];
    ws[idx] = f2bf(v);
  } else if (idx < 67584) {
    int i = idx - 65536;
    int n = i >> 7, k = i & 127;
    ws[idx] = f2bf((n < 4) ? W5[k * 4 + n] : 0.f);
  }
}

// 128 threads = 2 independent waves. Each wave runs TWO independent 32-row
// tile streams (interleaved for ILP) with wave-private LDS slabs; layers are
// split into two 16-row rb-passes (acc = 32 f32/stream; epilogue of pass rb
// only touches rows [rb*16,rb*16+16) so no intra-wave race). Zero barriers.
__global__ __launch_bounds__(128) void domino_main(
    const float* __restrict__ qp, const float* __restrict__ pts,
    const float* __restrict__ freqs,
    const float* __restrict__ b1, const float* __restrict__ b2,
    const float* __restrict__ b3, const float* __restrict__ b4,
    const float* __restrict__ b5, const int* __restrict__ mapping,
    const u16* __restrict__ wsW, float* __restrict__ out) {
  __shared__ alignas(16) u16 Abuf[2][2][32 * 128];   // [wave][tile] 8KB slabs

  const int tid  = threadIdx.x;
  const int lane = tid & 63;
  const int wid  = tid >> 6;
  const int l15  = lane & 15;
  const int lk   = lane >> 4;
  char* const abA = (char*)(Abuf[wid][0]);
  char* const abB = (char*)(Abuf[wid][1]);

  const int wg   = blockIdx.x * 2 + wid;   // global wave id, 0..16383
  const int row0 = wg * 64;                // tileA rows [row0,+32), tileB +32

  // ---- gather + fourier features for both tiles (independent streams) ----
  {
    const int rl = lane >> 1;              // local row 0..31
    const int p  = lane & 1;               // half of the 24 scaled features
    #pragma unroll
    for (int t = 0; t < 2; ++t) {
      char* const ab = t ? abB : abA;
      const int rg = row0 + t * 32 + rl;
      const int nb = mapping[rg];
      const int mg = rg >> 3;
      float rel[3];
      #pragma unroll
      for (int d = 0; d < 3; ++d) rel[d] = pts[nb * 3 + d] - qp[mg * 3 + d];
      float sv[12], cv[12];
      #pragma unroll
      for (int q = 0; q < 12; ++q) {       // j = p*12 + q ; f = j/3 ; d = j%3
        const int f = p * 4 + q / 3;
        const int d = q % 3;
        const float a = rel[d] * freqs[f];
        sv[q] = __sinf(a);
        cv[q] = __cosf(a);
      }
      u32 sw[6], cw[6];
      #pragma unroll
      for (int i = 0; i < 6; ++i) {
        sw[i] = (u32)f2bf(sv[2 * i]) | ((u32)f2bf(sv[2 * i + 1]) << 16);
        cw[i] = (u32)f2bf(cv[2 * i]) | ((u32)f2bf(cv[2 * i + 1]) << 16);
      }
      #pragma unroll
      for (int i = 0; i < 3; ++i) {
        u32x2 s2 = {sw[2 * i], sw[2 * i + 1]};
        *(u32x2*)(ab + swz(rl, p * 24 + i * 8)) = s2;        // sin cols [0,24)
        u32x2 c2 = {cw[2 * i], cw[2 * i + 1]};
        *(u32x2*)(ab + swz(rl, 48 + p * 24 + i * 8)) = c2;   // cos cols [24,48)
      }
      u32x4 z = {0, 0, 0, 0};                                // pad cols [48,64)
      *(u32x4*)(ab + swz(rl, 96 + p * 16)) = z;
    }
  }
  // within-wave LDS write->read: compiler's lgkmcnt handles it; no barrier.

  const float* const BS[4] = {b1, b2, b3, b4};

  #pragma unroll
  for (int layer = 0; layer < 4; ++layer) {
    const char* Wl = (const char*)(wsW + layer * 16384);
    // bias loads issue here; not consumed until the epilogue (huge slack)
    float bias[8];
    #pragma unroll
    for (int cb = 0; cb < 8; ++cb) bias[cb] = BS[layer][cb * 16 + l15];

    const int KKn = (layer == 0) ? 2 : 4;   // layer0: K=48 (padded to 64)

    #pragma unroll
    for (int rb = 0; rb < 2; ++rb) {
      f32x4 accA[8], accB[8];
      #pragma unroll
      for (int cb = 0; cb < 8; ++cb) {
        f32x4 z = {0.f, 0.f, 0.f, 0.f};
        accA[cb] = z;
        accB[cb] = z;
      }
      #pragma unroll
      for (int kk = 0; kk < 4; ++kk) {
        if (kk < KKn) {
          const short8 aA = *(const short8*)(abA + swz(rb * 16 + l15, kk * 64 + lk * 16));
          const short8 aB = *(const short8*)(abB + swz(rb * 16 + l15, kk * 64 + lk * 16));
          #pragma unroll
          for (int cb = 0; cb < 8; ++cb) {
            // one B-frag (global, L1/L2-hot) feeds BOTH tile streams
            const short8 bf =
                *(const short8*)(Wl + (cb * 16 + l15) * 256 + kk * 64 + lk * 16);
            accA[cb] = __builtin_amdgcn_mfma_f32_16x16x32_bf16(aA, bf, accA[cb], 0, 0, 0);
            accB[cb] = __builtin_amdgcn_mfma_f32_16x16x32_bf16(aB, bf, accB[cb], 0, 0, 0);
          }
        }
      }
      // epilogues: writes rows [rb*16,rb*16+16) only -> no race with rb1 reads
      #pragma unroll
      for (int t = 0; t < 2; ++t) {
        char* const ab = t ? abB : abA;
        const f32x4* const acc = t ? accB : accA;
        float m = 0.f;
        #pragma unroll
        for (int cb = 0; cb < 8; ++cb)
          #pragma unroll
          for (int rg = 0; rg < 4; ++rg)
            m = __builtin_fmaxf(m, __builtin_fabsf(acc[cb][rg] + bias[cb]));
        if (__any(m > 1.5f)) {               // rare wave-uniform fallback
          #pragma unroll
          for (int rg = 0; rg < 4; ++rg) {
            const int row = rb * 16 + lk * 4 + rg;
            #pragma unroll
            for (int cb = 0; cb < 8; ++cb)
              *(u16*)(ab + swz(row, (cb * 16 + l15) * 2)) =
                  f2bf(gelu_as(acc[cb][rg] + bias[cb]));
          }
        } else {
          #pragma unroll
          for (int rg = 0; rg < 4; ++rg) {
            const int row = rb * 16 + lk * 4 + rg;
            #pragma unroll
            for (int cb = 0; cb < 8; ++cb)
              *(u16*)(ab + swz(row, (cb * 16 + l15) * 2)) =
                  f2bf(gelu_poly(acc[cb][rg] + bias[cb]));
          }
        }
      }
    }
  }

  // ---- layer 5 per tile: [32x128] @ W5T[16x128], mean over 8 neighbors ----
  {
    const char* W5l = (const char*)(wsW + 65536);
    #pragma unroll
    for (int t = 0; t < 2; ++t) {
      char* const ab = t ? abB : abA;
      f32x4 acc5[2] = {{0.f, 0.f, 0.f, 0.f}, {0.f, 0.f, 0.f, 0.f}};
      #pragma unroll
      for (int kk = 0; kk < 4; ++kk) {
        const short8 a0 = *(const short8*)(ab + swz(l15,      kk * 64 + lk * 16));
        const short8 a1 = *(const short8*)(ab + swz(16 + l15, kk * 64 + lk * 16));
        const short8 bf = *(const short8*)(W5l + l15 * 256 + kk * 64 + lk * 16);
        acc5[0] = __builtin_amdgcn_mfma_f32_16x16x32_bf16(a0, bf, acc5[0], 0, 0, 0);
        acc5[1] = __builtin_amdgcn_mfma_f32_16x16x32_bf16(a1, bf, acc5[1], 0, 0, 0);
      }
      // D[col=l15=outfeat][row=lk*4+r=sample]; sum 4 in-lane samples, then
      // xor-16 joins lk pairs {0,1}/{2,3} -> 8-neighbor sums per query.
      float s40 = acc5[0][0] + acc5[0][1] + acc5[0][2] + acc5[0][3];
      float s41 = acc5[1][0] + acc5[1][1] + acc5[1][2] + acc5[1][3];
      s40 += __shfl_xor(s40, 16, 64);
      s41 += __shfl_xor(s41, 16, 64);
      if ((lk & 1) == 0 && l15 < 4) {
        const int q0 = (wg * 2 + t) * 4 + (lk >> 1);   // lk=0 -> +0 ; lk=2 -> +1
        const float bv = b5[l15];
        out[(q0)     * 4 + l15] = 0.125f * s40 + bv;   // rows 0..15: queries 0,1
        out[(q0 + 2) * 4 + l15] = 0.125f * s41 + bv;   // rows 16..31: queries 2,3
      }
    }
  }
}

extern "C" void kernel_launch(void* const* d_in, const int* in_sizes, int n_in,
                              void* d_out, int out_size, void* d_ws, size_t ws_size,
                              hipStream_t stream) {
  const float* qp      = (const float*)d_in[0];
  const float* pts     = (const float*)d_in[1];
  const float* freqs   = (const float*)d_in[2];
  const float* W1      = (const float*)d_in[3];
  const float* b1      = (const float*)d_in[4];
  const float* W2      = (const float*)d_in[5];
  const float* b2      = (const float*)d_in[6];
  const float* W3      = (const float*)d_in[7];
  const float* b3      = (const float*)d_in[8];
  const float* W4      = (const float*)d_in[9];
  const float* b4      = (const float*)d_in[10];
  const float* W5      = (const float*)d_in[11];
  const float* b5      = (const float*)d_in[12];
  const int*   mapping = (const int*)d_in[13];
  u16* ws = (u16*)d_ws;
  float* out = (float*)d_out;

  prep_weights<<<dim3(264), dim3(256), 0, stream>>>(W1, W2, W3, W4, W5, ws);
  // 16384 waves x 2 tiles x 32 rows = 1,048,576 rows; 2 waves/block
  domino_main<<<dim3(8192), dim3(128), 0, stream>>>(
      qp, pts, freqs, b1, b2, b3, b4, b5, mapping, ws, out);
}

// Round 7
// 477.548 us; speedup vs baseline: 1.3681x; 1.3681x over previous
//
#include <hip/hip_runtime.h>

typedef unsigned short u16;
typedef unsigned int u32;
typedef __attribute__((ext_vector_type(8))) short short8;
typedef __attribute__((ext_vector_type(4))) float f32x4;
typedef __attribute__((ext_vector_type(16))) float f32x16;
typedef __attribute__((ext_vector_type(4))) unsigned int u32x4;

__device__ __forceinline__ u16 f2bf(float f) {
  u32 u = __float_as_uint(f);
  u += 0x7FFFu + ((u >> 16) & 1u);
  return (u16)(u >> 16);
}

// packed f32x2 -> bf16x2 (RNE) HW op; elem0 = low 16 bits
__device__ __forceinline__ u32 cvt_pk_bf16(float lo, float hi) {
  u32 r;
  asm("v_cvt_pk_bf16_f32 %0, %1, %2" : "=v"(r) : "v"(lo), "v"(hi));
  return r;
}

// Pure-polynomial exact-GELU for |x| <= 1.5 (error < 3e-6 there).
__device__ __forceinline__ float gelu_poly(float x) {
  const float v = x * x;
  float p = __builtin_fmaf(-4.12267e-8f, v, 6.65969e-7f);
  p = __builtin_fmaf(p, v, -9.44466e-6f);
  p = __builtin_fmaf(p, v, 1.15437e-4f);
  p = __builtin_fmaf(p, v, -1.1873282e-3f);
  p = __builtin_fmaf(p, v, 9.973557e-3f);
  p = __builtin_fmaf(p, v, -6.649038e-2f);
  p = __builtin_fmaf(p, v, 0.3989422804f);
  return x * __builtin_fmaf(x, p, 0.5f);
}

// Fallback for rare |x| > 1.5: A&S 7.1.26 erfc (|err|~1.5e-7), branch-free.
__device__ __forceinline__ float gelu_as(float x) {
  float ax = __builtin_fabsf(0.70710678118654752f * x);
  float t  = __builtin_amdgcn_rcpf(__builtin_fmaf(0.3275911f, ax, 1.0f));
  float p  = __builtin_fmaf(__builtin_fmaf(__builtin_fmaf(__builtin_fmaf(
               0.5307027145f, t, -0.7265760135f), t, 0.7107068705f), t,
               -0.142248368f), t, 0.127414796f);
  float e  = __expf(-(ax * ax));
  float h  = (p * t) * e;
  float phi = (x >= 0.0f) ? (1.0f - h) : h;
  return x * phi;
}

// ---- prep ----
// ws u16 [0,65536): W1..W4 transposed [n=outfeat][k=infeat] (W1 k-padded
//   48->128 with row 48 = b1 for the constant-1 bias feature)
// ws u16 [65536,69632): W5T padded to [n=0..31][k=0..127] (n>=4 zero)
// ws f32 @byte 139264, 384 floats: layers 2..4 bias in D-fragment order:
//   [Lz][mb][hi][reg] = b[32mb + (reg&3) + 8(reg>>2) + 4hi]
__global__ void prep_weights(const float* __restrict__ W1, const float* __restrict__ b1,
                             const float* __restrict__ W2, const float* __restrict__ W3,
                             const float* __restrict__ W4, const float* __restrict__ W5,
                             const float* __restrict__ b2, const float* __restrict__ b3,
                             const float* __restrict__ b4, u16* __restrict__ ws) {
  int idx = blockIdx.x * 256 + threadIdx.x;
  if (idx < 65536) {
    int L = idx >> 14, rem = idx & 16383;
    int n = rem >> 7, k = rem & 127;
    float v;
    if (L == 0)      v = (k < 48) ? W1[k * 128 + n] : (k == 48 ? b1[n] : 0.f);
    else if (L == 1) v = W2[k * 128 + n];
    else if (L == 2) v = W3[k * 128 + n];
    else             v = W4[k * 128 + n];
    ws[idx] = f2bf(v);
  } else if (idx < 69632) {
    int i = idx - 65536;
    int n = i >> 7, k = i & 127;
    ws[idx] = f2bf((n < 4) ? W5[k * 4 + n] : 0.f);
  } else if (idx < 70016) {
    int t = idx - 69632;
    int Lz = t >> 7, rem = t & 127;
    int mb = rem >> 5, hi = (rem >> 4) & 1, r = rem & 15;
    const float* bl = (Lz == 0) ? b2 : (Lz == 1) ? b3 : b4;
    ((float*)ws)[34816 + t] = bl[mb * 32 + (r & 3) + 8 * (r >> 2) + 4 * hi];
  }
}

// GELU + repack one chunk's D (2 m-blocks, 32 f32/lane) into B-frags
// bnext[4c..4c+3] for the next layer. D rows: 32mb+(reg&3)+8(reg>>2)+4hi,
// col = sample = l31. B frag kk: k = 16kk + 8hi + j, col = l31.
__device__ __forceinline__ void gelu_pack(const f32x16& A0, const f32x16& A1,
                                          u32x4* bnext, int c, int hi) {
  float mx = 0.f;
  #pragma unroll
  for (int i = 0; i < 16; ++i)
    mx = __builtin_fmaxf(mx, __builtin_fmaxf(__builtin_fabsf(A0[i]),
                                             __builtin_fabsf(A1[i])));
  const bool safe = !__any(mx > 1.5f);
  #pragma unroll
  for (int t2 = 0; t2 < 4; ++t2) {
    const f32x16& D = (t2 < 2) ? A0 : A1;
    const int g4 = 8 * (t2 & 1);          // reg-quad pair g,g+1 (g=2*(t2&1))
    float e[8];
    if (safe) {
      #pragma unroll
      for (int i = 0; i < 8; ++i) e[i] = gelu_poly(D[g4 + i]);
    } else {
      #pragma unroll
      for (int i = 0; i < 8; ++i) e[i] = gelu_as(D[g4 + i]);
    }
    const u32 P0 = cvt_pk_bf16(e[0], e[1]);
    const u32 P1 = cvt_pk_bf16(e[2], e[3]);
    const u32 Q0 = cvt_pk_bf16(e[4], e[5]);
    const u32 Q1 = cvt_pk_bf16(e[6], e[7]);
    const u32 sP0 = __shfl_xor(P0, 32, 64);
    const u32 sP1 = __shfl_xor(P1, 32, 64);
    const u32 sQ0 = __shfl_xor(Q0, 32, 64);
    const u32 sQ1 = __shfl_xor(Q1, 32, 64);
    // lo lane: j0-3 = own P, j4-7 = partner's P (rows +4)
    // hi lane: j0-3 = partner's Q (rows +8), j4-7 = own Q (rows +12)
    u32x4 b;
    b.x = hi ? sQ0 : P0;
    b.y = hi ? sQ1 : P1;
    b.z = hi ? Q0 : sP0;
    b.w = hi ? Q1 : sP1;
    bnext[4 * c + t2] = b;
  }
}

// 256 threads = 4 fully independent waves; one wave = 32 samples (4 queries).
// Entire MLP in registers via transposed MFMA chaining. ZERO LDS, ZERO barriers.
__global__ __launch_bounds__(256) void domino_main(
    const float* __restrict__ qp, const float* __restrict__ pts,
    const float* __restrict__ freqs, const float* __restrict__ b5,
    const int* __restrict__ mapping, const u16* __restrict__ wsW,
    float* __restrict__ out) {
  const int lane = threadIdx.x & 63;
  const int wid  = threadIdx.x >> 6;
  const int wg   = blockIdx.x * 4 + wid;      // 0..32767
  const int l31  = lane & 31;
  const int hi   = lane >> 5;
  const char* const wbase = (const char*)wsW;
  const char* const bias_base = wbase + 139264;

  // ---- features, built directly in B-fragment layout ----
  const int s  = wg * 32 + l31;               // sample id (lo/hi duplicate)
  const int nb = mapping[s];
  const int mg = s >> 3;
  float rel[3];
  #pragma unroll
  for (int d = 0; d < 3; ++d) rel[d] = pts[nb * 3 + d] - qp[mg * 3 + d];
  float fq[8];
  #pragma unroll
  for (int f = 0; f < 8; ++f) fq[f] = freqs[f];
  // lane needs 24 of the 48 features; phase-select sin/cos per half:
  // lo: sin j0-7,16-23 + cos j8-15 ; hi: cos j0-7,16-23 + sin j8-15
  const float PH = 1.57079632679489662f;
  const float ph_mid = hi ? 0.f : PH;
  const float ph_out = hi ? PH : 0.f;
  float t[24];
  #pragma unroll
  for (int j = 0; j < 24; ++j) {
    const float a = __builtin_fmaf(rel[j % 3], fq[j / 3],
                                   (j >= 8 && j < 16) ? ph_mid : ph_out);
    t[j] = __sinf(a);
  }
  u32 pk[12];
  #pragma unroll
  for (int i = 0; i < 12; ++i) pk[i] = cvt_pk_bf16(t[2 * i], t[2 * i + 1]);

  u32x4 bcur[8];
  // k = 16kk + 8hi + j ; k<24: sin k ; 24<=k<48: cos(k-24) ; k=48: 1 ; else 0
  bcur[0] = hi ? (u32x4){pk[4], pk[5], pk[6], pk[7]}
               : (u32x4){pk[0], pk[1], pk[2], pk[3]};
  bcur[1] = hi ? (u32x4){pk[0], pk[1], pk[2], pk[3]}
               : (u32x4){pk[8], pk[9], pk[10], pk[11]};
  bcur[2] = hi ? (u32x4){pk[8], pk[9], pk[10], pk[11]}
               : (u32x4){pk[4], pk[5], pk[6], pk[7]};
  bcur[3] = (u32x4){hi ? 0u : 0x3F80u, 0u, 0u, 0u};   // bias-feature 1.0 @k=48

  // ---- layer 1: K=64 (4 kk), acc init 0 (bias folded into W row 48) ----
  {
    u32x4 bnext[8];
    #pragma unroll
    for (int c = 0; c < 2; ++c) {
      f32x16 A0, A1;
      #pragma unroll
      for (int i = 0; i < 16; ++i) { A0[i] = 0.f; A1[i] = 0.f; }
      #pragma unroll
      for (int kk = 0; kk < 4; ++kk) {
        const short8 w0 = *(const short8*)(wbase + ((2 * c) * 32 + l31) * 256 + kk * 32 + hi * 16);
        const short8 w1 = *(const short8*)(wbase + ((2 * c + 1) * 32 + l31) * 256 + kk * 32 + hi * 16);
        const short8 bf = __builtin_bit_cast(short8, bcur[kk]);
        A0 = __builtin_amdgcn_mfma_f32_32x32x16_bf16(w0, bf, A0, 0, 0, 0);
        A1 = __builtin_amdgcn_mfma_f32_32x32x16_bf16(w1, bf, A1, 0, 0, 0);
      }
      gelu_pack(A0, A1, bnext, c, hi);
    }
    #pragma unroll
    for (int kk = 0; kk < 8; ++kk) bcur[kk] = bnext[kk];
  }

  // ---- layers 2..4: K=128 (8 kk), acc init = bias fragment ----
  #pragma unroll
  for (int Lz = 0; Lz < 3; ++Lz) {
    const char* Wl = wbase + (Lz + 1) * 32768;
    const char* Bp = bias_base + Lz * 512;
    u32x4 bnext[8];
    #pragma unroll
    for (int c = 0; c < 2; ++c) {
      f32x16 A0, A1;
      #pragma unroll
      for (int q = 0; q < 4; ++q) {
        const f32x4 v0 = *(const f32x4*)(Bp + ((2 * c) * 2 + hi) * 64 + q * 16);
        const f32x4 v1 = *(const f32x4*)(Bp + ((2 * c + 1) * 2 + hi) * 64 + q * 16);
        #pragma unroll
        for (int e = 0; e < 4; ++e) { A0[q * 4 + e] = v0[e]; A1[q * 4 + e] = v1[e]; }
      }
      #pragma unroll
      for (int kk = 0; kk < 8; ++kk) {
        const short8 w0 = *(const short8*)(Wl + ((2 * c) * 32 + l31) * 256 + kk * 32 + hi * 16);
        const short8 w1 = *(const short8*)(Wl + ((2 * c + 1) * 32 + l31) * 256 + kk * 32 + hi * 16);
        const short8 bf = __builtin_bit_cast(short8, bcur[kk]);
        A0 = __builtin_amdgcn_mfma_f32_32x32x16_bf16(w0, bf, A0, 0, 0, 0);
        A1 = __builtin_amdgcn_mfma_f32_32x32x16_bf16(w1, bf, A1, 0, 0, 0);
      }
      gelu_pack(A0, A1, bnext, c, hi);
    }
    #pragma unroll
    for (int kk = 0; kk < 8; ++kk) bcur[kk] = bnext[kk];
  }

  // ---- layer 5: outfeat 0..3 live in lo-lane regs 0..3 ----
  {
    const char* W5l = wbase + 131072;
    f32x16 A5;
    #pragma unroll
    for (int i = 0; i < 16; ++i) A5[i] = 0.f;
    #pragma unroll
    for (int kk = 0; kk < 8; ++kk) {
      const short8 w = *(const short8*)(W5l + l31 * 256 + kk * 32 + hi * 16);
      A5 = __builtin_amdgcn_mfma_f32_32x32x16_bf16(
          w, __builtin_bit_cast(short8, bcur[kk]), A5, 0, 0, 0);
    }
    // mean over the 8 neighbors = lanes 8q..8q+7 (lo half)
    float r0 = A5[0], r1 = A5[1], r2 = A5[2], r3 = A5[3];
    #pragma unroll
    for (int d = 1; d < 8; d <<= 1) {
      r0 += __shfl_xor(r0, d, 64);
      r1 += __shfl_xor(r1, d, 64);
      r2 += __shfl_xor(r2, d, 64);
      r3 += __shfl_xor(r3, d, 64);
    }
    if (hi == 0 && (l31 & 7) == 0) {
      const f32x4 b5v = *(const f32x4*)b5;
      f32x4 o;
      o.x = __builtin_fmaf(0.125f, r0, b5v.x);
      o.y = __builtin_fmaf(0.125f, r1, b5v.y);
      o.z = __builtin_fmaf(0.125f, r2, b5v.z);
      o.w = __builtin_fmaf(0.125f, r3, b5v.w);
      *(f32x4*)(out + (wg * 4 + (l31 >> 3)) * 4) = o;
    }
  }
}

extern "C" void kernel_launch(void* const* d_in, const int* in_sizes, int n_in,
                              void* d_out, int out_size, void* d_ws, size_t ws_size,
                              hipStream_t stream) {
  const float* qp      = (const float*)d_in[0];
  const float* pts     = (const float*)d_in[1];
  const float* freqs   = (const float*)d_in[2];
  const float* W1      = (const float*)d_in[3];
  const float* b1      = (const float*)d_in[4];
  const float* W2      = (const float*)d_in[5];
  const float* b2      = (const float*)d_in[6];
  const float* W3      = (const float*)d_in[7];
  const float* b3      = (const float*)d_in[8];
  const float* W4      = (const float*)d_in[9];
  const float* b4      = (const float*)d_in[10];
  const float* W5      = (const float*)d_in[11];
  const float* b5      = (const float*)d_in[12];
  const int*   mapping = (const int*)d_in[13];
  u16* ws = (u16*)d_ws;
  float* out = (float*)d_out;

  prep_weights<<<dim3(274), dim3(256), 0, stream>>>(
      W1, b1, W2, W3, W4, W5, b2, b3, b4, ws);
  // 32768 waves x 32 samples = 1,048,576 ; 4 independent waves per block
  domino_main<<<dim3(8192), dim3(256), 0, stream>>>(
      qp, pts, freqs, b5, mapping, ws, out);
}

// Round 9
// 309.624 us; speedup vs baseline: 2.1101x; 1.5423x over previous
//
#include <hip/hip_runtime.h>

typedef unsigned short u16;
typedef unsigned int u32;
typedef __attribute__((ext_vector_type(8))) short short8;
typedef __attribute__((ext_vector_type(4))) float f32x4;
typedef __attribute__((ext_vector_type(16))) float f32x16;
typedef __attribute__((ext_vector_type(4))) unsigned int u32x4;

#define AS1 __attribute__((address_space(1)))
#define AS3 __attribute__((address_space(3)))

__device__ __forceinline__ u16 f2bf(float f) {
  u32 u = __float_as_uint(f);
  u += 0x7FFFu + ((u >> 16) & 1u);
  return (u16)(u >> 16);
}

// packed f32x2 -> bf16x2 (RNE) HW op; elem0 = low 16 bits
__device__ __forceinline__ u32 cvt_pk_bf16(float lo, float hi) {
  u32 r;
  asm("v_cvt_pk_bf16_f32 %0, %1, %2" : "=v"(r) : "v"(lo), "v"(hi));
  return r;
}

// Pure-polynomial exact-GELU for |x| <= 1.5 (error < 3e-6 there).
__device__ __forceinline__ float gelu_poly(float x) {
  const float v = x * x;
  float p = __builtin_fmaf(-4.12267e-8f, v, 6.65969e-7f);
  p = __builtin_fmaf(p, v, -9.44466e-6f);
  p = __builtin_fmaf(p, v, 1.15437e-4f);
  p = __builtin_fmaf(p, v, -1.1873282e-3f);
  p = __builtin_fmaf(p, v, 9.973557e-3f);
  p = __builtin_fmaf(p, v, -6.649038e-2f);
  p = __builtin_fmaf(p, v, 0.3989422804f);
  return x * __builtin_fmaf(x, p, 0.5f);
}

// Fallback for rare |x| > 1.5: A&S 7.1.26 erfc (|err|~1.5e-7), branch-free.
__device__ __forceinline__ float gelu_as(float x) {
  float ax = __builtin_fabsf(0.70710678118654752f * x);
  float t  = __builtin_amdgcn_rcpf(__builtin_fmaf(0.3275911f, ax, 1.0f));
  float p  = __builtin_fmaf(__builtin_fmaf(__builtin_fmaf(__builtin_fmaf(
               0.5307027145f, t, -0.7265760135f), t, 0.7107068705f), t,
               -0.142248368f), t, 0.127414796f);
  float e  = __expf(-(ax * ax));
  float h  = (p * t) * e;
  float phi = (x >= 0.0f) ? (1.0f - h) : h;
  return x * phi;
}

// ---- prep (R7 layout, with W1..W4 PRE-SWIZZLED within each 256B row so the
// main kernel stages them LINEARLY into LDS and ds_reads apply the XOR) ----
// ws u16 [0,65536): W1..W4 transposed [n=outfeat][k=infeat], element position
//   kp within row n holds source k = kp ^ ((n&7)<<3)   (W1 k-padded 48->128
//   with row k=48 = b1 for the constant-1 bias feature)
// ws u16 [65536,69632): W5T padded [n=0..31][k=0..127], PLAIN (read from
//   global by main, exactly as R7)
// ws f32 @byte 139264, 384 floats: layers 2..4 bias in D-fragment order:
//   [Lz][mb][hi][reg] = b[32mb + (reg&3) + 8(reg>>2) + 4hi]   (R7 verbatim)
__global__ void prep_weights(const float* __restrict__ W1, const float* __restrict__ b1,
                             const float* __restrict__ W2, const float* __restrict__ W3,
                             const float* __restrict__ W4, const float* __restrict__ W5,
                             const float* __restrict__ b2, const float* __restrict__ b3,
                             const float* __restrict__ b4, u16* __restrict__ ws) {
  int idx = blockIdx.x * 256 + threadIdx.x;
  if (idx < 65536) {
    int L = idx >> 14, rem = idx & 16383;
    int n = rem >> 7, kp = rem & 127;
    int k = kp ^ ((n & 7) << 3);        // pre-swizzle: dest kp holds source k
    float v;
    if (L == 0)      v = (k < 48) ? W1[k * 128 + n] : (k == 48 ? b1[n] : 0.f);
    else if (L == 1) v = W2[k * 128 + n];
    else if (L == 2) v = W3[k * 128 + n];
    else             v = W4[k * 128 + n];
    ws[idx] = f2bf(v);
  } else if (idx < 69632) {
    int i = idx - 65536;
    int n = i >> 7, k = i & 127;
    ws[idx] = f2bf((n < 4) ? W5[k * 4 + n] : 0.f);
  } else if (idx < 70016) {
    int t = idx - 69632;
    int Lz = t >> 7, rem = t & 127;
    int mb = rem >> 5, hi = (rem >> 4) & 1, r = rem & 15;
    const float* bl = (Lz == 0) ? b2 : (Lz == 1) ? b3 : b4;
    ((float*)ws)[34816 + t] = bl[mb * 32 + (r & 3) + 8 * (r >> 2) + 4 * hi];
  }
}

// GELU + repack one chunk's D (2 m-blocks, 32 f32/lane) into B-frags
// bnext[4c..4c+3] for the next layer. D rows: 32mb+(reg&3)+8(reg>>2)+4hi,
// col = sample = l31. B frag kk: k = 16kk + 8hi + j, col = l31.  (R7 verbatim)
__device__ __forceinline__ void gelu_pack(const f32x16& A0, const f32x16& A1,
                                          u32x4* bnext, int c, int hi) {
  float mx = 0.f;
  #pragma unroll
  for (int i = 0; i < 16; ++i)
    mx = __builtin_fmaxf(mx, __builtin_fmaxf(__builtin_fabsf(A0[i]),
                                             __builtin_fabsf(A1[i])));
  const bool safe = !__any(mx > 1.5f);
  #pragma unroll
  for (int t2 = 0; t2 < 4; ++t2) {
    const f32x16& D = (t2 < 2) ? A0 : A1;
    const int g4 = 8 * (t2 & 1);          // reg-quad pair g,g+1 (g=2*(t2&1))
    float e[8];
    if (safe) {
      #pragma unroll
      for (int i = 0; i < 8; ++i) e[i] = gelu_poly(D[g4 + i]);
    } else {
      #pragma unroll
      for (int i = 0; i < 8; ++i) e[i] = gelu_as(D[g4 + i]);
    }
    const u32 P0 = cvt_pk_bf16(e[0], e[1]);
    const u32 P1 = cvt_pk_bf16(e[2], e[3]);
    const u32 Q0 = cvt_pk_bf16(e[4], e[5]);
    const u32 Q1 = cvt_pk_bf16(e[6], e[7]);
    const u32 sP0 = __shfl_xor(P0, 32, 64);
    const u32 sP1 = __shfl_xor(P1, 32, 64);
    const u32 sQ0 = __shfl_xor(Q0, 32, 64);
    const u32 sQ1 = __shfl_xor(Q1, 32, 64);
    // lo lane: j0-3 = own P, j4-7 = partner's P (rows +4)
    // hi lane: j0-3 = partner's Q (rows +8), j4-7 = own Q (rows +12)
    u32x4 b;
    b.x = hi ? sQ0 : P0;
    b.y = hi ? sQ1 : P1;
    b.z = hi ? Q0 : sP0;
    b.w = hi ? Q1 : sP1;
    bnext[4 * c + t2] = b;
  }
}

// One 1024-thread block (16 waves) stages W1..W4 (128KB, pre-swizzled) into
// LDS once -> ONE barrier. Each wave then independently runs 4 x 32-sample
// passes with the R7-verbatim register-resident transposed-MFMA chain; only
// the W1..W4 fragment reads moved global->LDS (swizzled ds_read_b128).
__global__ __launch_bounds__(1024) void domino_main(
    const float* __restrict__ qp, const float* __restrict__ pts,
    const float* __restrict__ freqs, const float* __restrict__ b5,
    const int* __restrict__ mapping, const u16* __restrict__ wsW,
    float* __restrict__ out) {
  __shared__ alignas(16) char W[131072];
  const int tid = threadIdx.x;
  const int wid = tid >> 6;

  // ---- stage W1..W4 linearly (8 x 16KB chunks) ----
  {
    const char* src = (const char*)wsW;
    #pragma unroll
    for (int c = 0; c < 8; ++c)
      __builtin_amdgcn_global_load_lds(
          (const AS1 void*)(const void*)(src + c * 16384 + tid * 16),
          (AS3 void*)(void*)(W + c * 16384 + wid * 1024), 16, 0, 0);
  }
  __syncthreads();   // the ONLY barrier: drains DMA; W read-only afterwards

  const int lane = tid & 63;
  const int l31  = lane & 31;
  const int hi   = lane >> 5;
  const int swl  = (l31 & 7) << 4;        // lane-constant row-XOR (row&7=l31&7)
  const char* const wbase = (const char*)wsW;
  const char* const bias_base = wbase + 139264;

  // lane needs 24 of the 48 features; phase-select sin/cos per half:
  // lo: sin j0-7,16-23 + cos j8-15 ; hi: cos j0-7,16-23 + sin j8-15
  const float PH = 1.57079632679489662f;
  const float ph_mid = hi ? 0.f : PH;
  const float ph_out = hi ? PH : 0.f;
  float fq[8];
  #pragma unroll
  for (int f = 0; f < 8; ++f) fq[f] = freqs[f];

  const int gw = blockIdx.x * 16 + wid;   // 0..8191

  for (int it = 0; it < 4; ++it) {
    const int wg = gw * 4 + it;           // 0..32767 (R7's wave id)

    // ---- features, built directly in B-fragment layout (R7 verbatim) ----
    const int s  = wg * 32 + l31;         // sample id (lo/hi duplicate)
    const int nb = mapping[s];
    const int mg = s >> 3;
    float rel[3];
    #pragma unroll
    for (int d = 0; d < 3; ++d) rel[d] = pts[nb * 3 + d] - qp[mg * 3 + d];
    float t[24];
    #pragma unroll
    for (int j = 0; j < 24; ++j) {
      const float a = __builtin_fmaf(rel[j % 3], fq[j / 3],
                                     (j >= 8 && j < 16) ? ph_mid : ph_out);
      t[j] = __sinf(a);
    }
    u32 pk[12];
    #pragma unroll
    for (int i = 0; i < 12; ++i) pk[i] = cvt_pk_bf16(t[2 * i], t[2 * i + 1]);

    u32x4 bcur[8];
    // k = 16kk + 8hi + j ; k<24: sin k ; 24<=k<48: cos(k-24) ; k=48: 1 ; else 0
    bcur[0] = hi ? (u32x4){pk[4], pk[5], pk[6], pk[7]}
                 : (u32x4){pk[0], pk[1], pk[2], pk[3]};
    bcur[1] = hi ? (u32x4){pk[0], pk[1], pk[2], pk[3]}
                 : (u32x4){pk[8], pk[9], pk[10], pk[11]};
    bcur[2] = hi ? (u32x4){pk[8], pk[9], pk[10], pk[11]}
                 : (u32x4){pk[4], pk[5], pk[6], pk[7]};
    bcur[3] = (u32x4){hi ? 0u : 0x3F80u, 0u, 0u, 0u}; // bias-feature 1.0 @k=48

    // ---- layer 1: K=64 (4 kk), acc init 0 (bias folded into W row 48) ----
    {
      u32x4 bnext[8];
      #pragma unroll
      for (int c = 0; c < 2; ++c) {
        f32x16 A0, A1;
        #pragma unroll
        for (int i = 0; i < 16; ++i) { A0[i] = 0.f; A1[i] = 0.f; }
        #pragma unroll
        for (int kk = 0; kk < 4; ++kk) {
          const short8 w0 = *(const short8*)(W + ((((2 * c) * 32 + l31) * 256 + kk * 32 + hi * 16) ^ swl));
          const short8 w1 = *(const short8*)(W + ((((2 * c + 1) * 32 + l31) * 256 + kk * 32 + hi * 16) ^ swl));
          const short8 bf = __builtin_bit_cast(short8, bcur[kk]);
          A0 = __builtin_amdgcn_mfma_f32_32x32x16_bf16(w0, bf, A0, 0, 0, 0);
          A1 = __builtin_amdgcn_mfma_f32_32x32x16_bf16(w1, bf, A1, 0, 0, 0);
        }
        gelu_pack(A0, A1, bnext, c, hi);
      }
      #pragma unroll
      for (int kk = 0; kk < 8; ++kk) bcur[kk] = bnext[kk];
    }

    // ---- layers 2..4: K=128 (8 kk), acc init = bias fragment ----
    #pragma unroll
    for (int Lz = 0; Lz < 3; ++Lz) {
      const char* Wl = W + (Lz + 1) * 32768;
      const char* Bp = bias_base + Lz * 512;
      u32x4 bnext[8];
      #pragma unroll
      for (int c = 0; c < 2; ++c) {
        f32x16 A0, A1;
        #pragma unroll
        for (int q = 0; q < 4; ++q) {
          const f32x4 v0 = *(const f32x4*)(Bp + ((2 * c) * 2 + hi) * 64 + q * 16);
          const f32x4 v1 = *(const f32x4*)(Bp + ((2 * c + 1) * 2 + hi) * 64 + q * 16);
          #pragma unroll
          for (int e = 0; e < 4; ++e) { A0[q * 4 + e] = v0[e]; A1[q * 4 + e] = v1[e]; }
        }
        #pragma unroll
        for (int kk = 0; kk < 8; ++kk) {
          const short8 w0 = *(const short8*)(Wl + ((((2 * c) * 32 + l31) * 256 + kk * 32 + hi * 16) ^ swl));
          const short8 w1 = *(const short8*)(Wl + ((((2 * c + 1) * 32 + l31) * 256 + kk * 32 + hi * 16) ^ swl));
          const short8 bf = __builtin_bit_cast(short8, bcur[kk]);
          A0 = __builtin_amdgcn_mfma_f32_32x32x16_bf16(w0, bf, A0, 0, 0, 0);
          A1 = __builtin_amdgcn_mfma_f32_32x32x16_bf16(w1, bf, A1, 0, 0, 0);
        }
        gelu_pack(A0, A1, bnext, c, hi);
      }
      #pragma unroll
      for (int kk = 0; kk < 8; ++kk) bcur[kk] = bnext[kk];
    }

    // ---- layer 5: from GLOBAL exactly as R7 (tiny, 8 loads/iter) ----
    {
      const char* W5l = wbase + 131072;
      f32x16 A5;
      #pragma unroll
      for (int i = 0; i < 16; ++i) A5[i] = 0.f;
      #pragma unroll
      for (int kk = 0; kk < 8; ++kk) {
        const short8 w = *(const short8*)(W5l + l31 * 256 + kk * 32 + hi * 16);
        A5 = __builtin_amdgcn_mfma_f32_32x32x16_bf16(
            w, __builtin_bit_cast(short8, bcur[kk]), A5, 0, 0, 0);
      }
      // mean over the 8 neighbors = lanes 8q..8q+7 (lo half)
      float r0 = A5[0], r1 = A5[1], r2 = A5[2], r3 = A5[3];
      #pragma unroll
      for (int d = 1; d < 8; d <<= 1) {
        r0 += __shfl_xor(r0, d, 64);
        r1 += __shfl_xor(r1, d, 64);
        r2 += __shfl_xor(r2, d, 64);
        r3 += __shfl_xor(r3, d, 64);
      }
      if (hi == 0 && (l31 & 7) == 0) {
        const f32x4 b5v = *(const f32x4*)b5;
        f32x4 o;
        o.x = __builtin_fmaf(0.125f, r0, b5v.x);
        o.y = __builtin_fmaf(0.125f, r1, b5v.y);
        o.z = __builtin_fmaf(0.125f, r2, b5v.z);
        o.w = __builtin_fmaf(0.125f, r3, b5v.w);
        *(f32x4*)(out + (wg * 4 + (l31 >> 3)) * 4) = o;
      }
    }
  }
}

extern "C" void kernel_launch(void* const* d_in, const int* in_sizes, int n_in,
                              void* d_out, int out_size, void* d_ws, size_t ws_size,
                              hipStream_t stream) {
  const float* qp      = (const float*)d_in[0];
  const float* pts     = (const float*)d_in[1];
  const float* freqs   = (const float*)d_in[2];
  const float* W1      = (const float*)d_in[3];
  const float* b1      = (const float*)d_in[4];
  const float* W2      = (const float*)d_in[5];
  const float* b2      = (const float*)d_in[6];
  const float* W3      = (const float*)d_in[7];
  const float* b3      = (const float*)d_in[8];
  const float* W4      = (const float*)d_in[9];
  const float* b4      = (const float*)d_in[10];
  const float* W5      = (const float*)d_in[11];
  const float* b5      = (const float*)d_in[12];
  const int*   mapping = (const int*)d_in[13];
  u16* ws = (u16*)d_ws;
  float* out = (float*)d_out;

  prep_weights<<<dim3(274), dim3(256), 0, stream>>>(
      W1, b1, W2, W3, W4, W5, b2, b3, b4, ws);
  // 512 blocks x 16 waves x 4 iters x 32 samples = 1,048,576 rows
  domino_main<<<dim3(512), dim3(1024), 0, stream>>>(
      qp, pts, freqs, b5, mapping, ws, out);
}

// Round 10
// 256.853 us; speedup vs baseline: 2.5436x; 1.2055x over previous
//
#include <hip/hip_runtime.h>

typedef unsigned short u16;
typedef unsigned int u32;
typedef __attribute__((ext_vector_type(8))) short short8;
typedef __attribute__((ext_vector_type(2))) float f32x2;
typedef __attribute__((ext_vector_type(4))) float f32x4;
typedef __attribute__((ext_vector_type(16))) float f32x16;
typedef __attribute__((ext_vector_type(4))) unsigned int u32x4;

#define AS1 __attribute__((address_space(1)))
#define AS3 __attribute__((address_space(3)))

__device__ __forceinline__ u16 f2bf(float f) {
  u32 u = __float_as_uint(f);
  u += 0x7FFFu + ((u >> 16) & 1u);
  return (u16)(u >> 16);
}

// packed f32x2 -> bf16x2 (RNE) HW op; elem0 = low 16 bits
__device__ __forceinline__ u32 cvt_pk_bf16(float lo, float hi) {
  u32 r;
  asm("v_cvt_pk_bf16_f32 %0, %1, %2" : "=v"(r) : "v"(lo), "v"(hi));
  return r;
}

// Pure-polynomial exact-GELU for |x| <= 1.5 (error < 3e-6 there), on f32x2
// pairs so the compiler can emit v_pk_fma_f32 (halves VALU issue slots).
// Identical coefficients/order to the scalar R9 version -> bit-identical.
__device__ __forceinline__ f32x2 gelu_poly2(f32x2 x) {
  const f32x2 v = x * x;
  f32x2 p = __builtin_elementwise_fma(v, (f32x2)(-4.12267e-8f), (f32x2)(6.65969e-7f));
  p = __builtin_elementwise_fma(p, v, (f32x2)(-9.44466e-6f));
  p = __builtin_elementwise_fma(p, v, (f32x2)(1.15437e-4f));
  p = __builtin_elementwise_fma(p, v, (f32x2)(-1.1873282e-3f));
  p = __builtin_elementwise_fma(p, v, (f32x2)(9.973557e-3f));
  p = __builtin_elementwise_fma(p, v, (f32x2)(-6.649038e-2f));
  p = __builtin_elementwise_fma(p, v, (f32x2)(0.3989422804f));
  return x * __builtin_elementwise_fma(x, p, (f32x2)0.5f);
}

// Fallback for rare |x| > 1.5: A&S 7.1.26 erfc (|err|~1.5e-7), branch-free.
__device__ __forceinline__ float gelu_as(float x) {
  float ax = __builtin_fabsf(0.70710678118654752f * x);
  float t  = __builtin_amdgcn_rcpf(__builtin_fmaf(0.3275911f, ax, 1.0f));
  float p  = __builtin_fmaf(__builtin_fmaf(__builtin_fmaf(__builtin_fmaf(
               0.5307027145f, t, -0.7265760135f), t, 0.7107068705f), t,
               -0.142248368f), t, 0.127414796f);
  float e  = __expf(-(ax * ax));
  float h  = (p * t) * e;
  float phi = (x >= 0.0f) ? (1.0f - h) : h;
  return x * phi;
}

// ---- prep: one contiguous 140800-byte LDS image in ws, staged LINEARLY by
// main via global_load_lds; swizzled regions pre-apply the XOR involution.
// bytes [0,131072):       W1..W4 transposed [n][kp], kp holds k = kp^((n&7)<<3)
//                         (W1 k-padded 48->128, row k=48 = b1 bias feature)
// bytes [131072,139264):  W5T padded [n=0..31][kp], same pre-swizzle
// bytes [139264,140800):  384 f32, layers 2..4 bias in D-fragment order:
//                         [Lz][mb][hi][reg] = b[32mb + (r&3) + 8(r>>2) + 4hi]
__global__ void prep_weights(const float* __restrict__ W1, const float* __restrict__ b1,
                             const float* __restrict__ W2, const float* __restrict__ W3,
                             const float* __restrict__ W4, const float* __restrict__ W5,
                             const float* __restrict__ b2, const float* __restrict__ b3,
                             const float* __restrict__ b4, u16* __restrict__ ws) {
  int idx = blockIdx.x * 256 + threadIdx.x;
  if (idx < 65536) {
    int L = idx >> 14, rem = idx & 16383;
    int n = rem >> 7, kp = rem & 127;
    int k = kp ^ ((n & 7) << 3);        // pre-swizzle: dest kp holds source k
    float v;
    if (L == 0)      v = (k < 48) ? W1[k * 128 + n] : (k == 48 ? b1[n] : 0.f);
    else if (L == 1) v = W2[k * 128 + n];
    else if (L == 2) v = W3[k * 128 + n];
    else             v = W4[k * 128 + n];
    ws[idx] = f2bf(v);
  } else if (idx < 69632) {
    int i = idx - 65536;
    int n = i >> 7, kp = i & 127;
    int k = kp ^ ((n & 7) << 3);        // W5 pre-swizzled too (now LDS-served)
    ws[idx] = f2bf((n < 4) ? W5[k * 4 + n] : 0.f);
  } else if (idx < 70016) {
    int t = idx - 69632;
    int Lz = t >> 7, rem = t & 127;
    int mb = rem >> 5, hi = (rem >> 4) & 1, r = rem & 15;
    const float* bl = (Lz == 0) ? b2 : (Lz == 1) ? b3 : b4;
    ((float*)ws)[34816 + t] = bl[mb * 32 + (r & 3) + 8 * (r >> 2) + 4 * hi];
  }
}

// GELU + repack one chunk's D (2 m-blocks, 32 f32/lane) into B-frags
// bnext[4c..4c+3] for the next layer. D rows: 32mb+(reg&3)+8(reg>>2)+4hi,
// col = sample = l31. B frag kk: k = 16kk + 8hi + j, col = l31.
__device__ __forceinline__ void gelu_pack(const f32x16& A0, const f32x16& A1,
                                          u32x4* bnext, int c, int hi) {
  // max3-fused guard (fabs folds into v_max3 input modifiers)
  float mx = 0.f;
  #pragma unroll
  for (int i = 0; i < 16; i += 2) {
    mx = __builtin_fmaxf(mx, __builtin_fmaxf(__builtin_fabsf(A0[i]),
                                             __builtin_fabsf(A0[i + 1])));
    mx = __builtin_fmaxf(mx, __builtin_fmaxf(__builtin_fabsf(A1[i]),
                                             __builtin_fabsf(A1[i + 1])));
  }
  const bool safe = !__any(mx > 1.5f);
  #pragma unroll
  for (int t2 = 0; t2 < 4; ++t2) {
    const f32x16& D = (t2 < 2) ? A0 : A1;
    const int g4 = 8 * (t2 & 1);          // reg-quad pair g,g+1 (g=2*(t2&1))
    float e[8];
    if (safe) {
      #pragma unroll
      for (int i = 0; i < 8; i += 2) {
        const f32x2 g = gelu_poly2((f32x2){D[g4 + i], D[g4 + i + 1]});
        e[i] = g.x; e[i + 1] = g.y;
      }
    } else {
      #pragma unroll
      for (int i = 0; i < 8; ++i) e[i] = gelu_as(D[g4 + i]);
    }
    const u32 P0 = cvt_pk_bf16(e[0], e[1]);
    const u32 P1 = cvt_pk_bf16(e[2], e[3]);
    const u32 Q0 = cvt_pk_bf16(e[4], e[5]);
    const u32 Q1 = cvt_pk_bf16(e[6], e[7]);
    const u32 sP0 = __shfl_xor(P0, 32, 64);
    const u32 sP1 = __shfl_xor(P1, 32, 64);
    const u32 sQ0 = __shfl_xor(Q0, 32, 64);
    const u32 sQ1 = __shfl_xor(Q1, 32, 64);
    // lo lane: j0-3 = own P, j4-7 = partner's P (rows +4)
    // hi lane: j0-3 = partner's Q (rows +8), j4-7 = own Q (rows +12)
    u32x4 b;
    b.x = hi ? sQ0 : P0;
    b.y = hi ? sQ1 : P1;
    b.z = hi ? Q0 : sP0;
    b.w = hi ? Q1 : sP1;
    bnext[4 * c + t2] = b;
  }
}

// One 1024-thread block (16 waves) stages the FULL weight image (W1..W5 +
// bias quads, 137.5KB, pre-swizzled) into LDS once -> ONE barrier. Each wave
// independently runs 4 x 32-sample register-resident transposed-MFMA passes.
// No global reads in the layer chain except mapping/pts/qp (features) and b5.
__global__ __launch_bounds__(1024) void domino_main(
    const float* __restrict__ qp, const float* __restrict__ pts,
    const float* __restrict__ freqs, const float* __restrict__ b5,
    const int* __restrict__ mapping, const u16* __restrict__ wsW,
    float* __restrict__ out) {
  __shared__ alignas(16) char W[140800];
  const int tid = threadIdx.x;
  const int wid = tid >> 6;

  // ---- stage image linearly: 8 x 16KB chunks + 9728B tail ----
  {
    const char* src = (const char*)wsW;
    #pragma unroll
    for (int c = 0; c < 8; ++c)
      __builtin_amdgcn_global_load_lds(
          (const AS1 void*)(const void*)(src + c * 16384 + tid * 16),
          (AS3 void*)(void*)(W + c * 16384 + wid * 1024), 16, 0, 0);
    if (tid * 16 < 9728)   // lane-predicated tail; holes past image are unused
      __builtin_amdgcn_global_load_lds(
          (const AS1 void*)(const void*)(src + 131072 + tid * 16),
          (AS3 void*)(void*)(W + 131072 + wid * 1024), 16, 0, 0);
  }
  __syncthreads();   // the ONLY barrier: drains DMA; W read-only afterwards

  const int lane = tid & 63;
  const int l31  = lane & 31;
  const int hi   = lane >> 5;
  const int swl  = (l31 & 7) << 4;        // lane-constant row-XOR (row&7=l31&7)

  // lane needs 24 of the 48 features; phase-select sin/cos per half:
  // lo: sin j0-7,16-23 + cos j8-15 ; hi: cos j0-7,16-23 + sin j8-15
  const float PH = 1.57079632679489662f;
  const float ph_mid = hi ? 0.f : PH;
  const float ph_out = hi ? PH : 0.f;
  float fq[8];
  #pragma unroll
  for (int f = 0; f < 8; ++f) fq[f] = freqs[f];

  const int gw = blockIdx.x * 16 + wid;   // 0..8191

  for (int it = 0; it < 4; ++it) {
    const int wg = gw * 4 + it;           // 0..32767

    // ---- features, built directly in B-fragment layout ----
    const int s  = wg * 32 + l31;         // sample id (lo/hi duplicate)
    const int nb = mapping[s];
    const int mg = s >> 3;
    float rel[3];
    #pragma unroll
    for (int d = 0; d < 3; ++d) rel[d] = pts[nb * 3 + d] - qp[mg * 3 + d];
    float t[24];
    #pragma unroll
    for (int j = 0; j < 24; ++j) {
      const float a = __builtin_fmaf(rel[j % 3], fq[j / 3],
                                     (j >= 8 && j < 16) ? ph_mid : ph_out);
      t[j] = __sinf(a);
    }
    u32 pk[12];
    #pragma unroll
    for (int i = 0; i < 12; ++i) pk[i] = cvt_pk_bf16(t[2 * i], t[2 * i + 1]);

    u32x4 bcur[8];
    // k = 16kk + 8hi + j ; k<24: sin k ; 24<=k<48: cos(k-24) ; k=48: 1 ; else 0
    bcur[0] = hi ? (u32x4){pk[4], pk[5], pk[6], pk[7]}
                 : (u32x4){pk[0], pk[1], pk[2], pk[3]};
    bcur[1] = hi ? (u32x4){pk[0], pk[1], pk[2], pk[3]}
                 : (u32x4){pk[8], pk[9], pk[10], pk[11]};
    bcur[2] = hi ? (u32x4){pk[8], pk[9], pk[10], pk[11]}
                 : (u32x4){pk[4], pk[5], pk[6], pk[7]};
    bcur[3] = (u32x4){hi ? 0u : 0x3F80u, 0u, 0u, 0u}; // bias-feature 1.0 @k=48

    // ---- layer 1: K=64 (4 kk), acc init 0 (bias folded into W row 48) ----
    {
      u32x4 bnext[8];
      #pragma unroll
      for (int c = 0; c < 2; ++c) {
        f32x16 A0, A1;
        #pragma unroll
        for (int i = 0; i < 16; ++i) { A0[i] = 0.f; A1[i] = 0.f; }
        #pragma unroll
        for (int kk = 0; kk < 4; ++kk) {
          const short8 w0 = *(const short8*)(W + ((((2 * c) * 32 + l31) * 256 + kk * 32 + hi * 16) ^ swl));
          const short8 w1 = *(const short8*)(W + ((((2 * c + 1) * 32 + l31) * 256 + kk * 32 + hi * 16) ^ swl));
          const short8 bf = __builtin_bit_cast(short8, bcur[kk]);
          A0 = __builtin_amdgcn_mfma_f32_32x32x16_bf16(w0, bf, A0, 0, 0, 0);
          A1 = __builtin_amdgcn_mfma_f32_32x32x16_bf16(w1, bf, A1, 0, 0, 0);
        }
        gelu_pack(A0, A1, bnext, c, hi);
      }
      #pragma unroll
      for (int kk = 0; kk < 8; ++kk) bcur[kk] = bnext[kk];
    }

    // ---- layers 2..4: K=128 (8 kk), acc init = bias fragment (LDS) ----
    #pragma unroll
    for (int Lz = 0; Lz < 3; ++Lz) {
      const char* Wl = W + (Lz + 1) * 32768;
      const char* Bp = W + 139264 + Lz * 512;
      u32x4 bnext[8];
      #pragma unroll
      for (int c = 0; c < 2; ++c) {
        f32x16 A0, A1;
        #pragma unroll
        for (int q = 0; q < 4; ++q) {
          const f32x4 v0 = *(const f32x4*)(Bp + ((2 * c) * 2 + hi) * 64 + q * 16);
          const f32x4 v1 = *(const f32x4*)(Bp + ((2 * c + 1) * 2 + hi) * 64 + q * 16);
          #pragma unroll
          for (int e = 0; e < 4; ++e) { A0[q * 4 + e] = v0[e]; A1[q * 4 + e] = v1[e]; }
        }
        #pragma unroll
        for (int kk = 0; kk < 8; ++kk) {
          const short8 w0 = *(const short8*)(Wl + ((((2 * c) * 32 + l31) * 256 + kk * 32 + hi * 16) ^ swl));
          const short8 w1 = *(const short8*)(Wl + ((((2 * c + 1) * 32 + l31) * 256 + kk * 32 + hi * 16) ^ swl));
          const short8 bf = __builtin_bit_cast(short8, bcur[kk]);
          A0 = __builtin_amdgcn_mfma_f32_32x32x16_bf16(w0, bf, A0, 0, 0, 0);
          A1 = __builtin_amdgcn_mfma_f32_32x32x16_bf16(w1, bf, A1, 0, 0, 0);
        }
        gelu_pack(A0, A1, bnext, c, hi);
      }
      #pragma unroll
      for (int kk = 0; kk < 8; ++kk) bcur[kk] = bnext[kk];
    }

    // ---- layer 5: now from LDS (swizzled like W1..W4) ----
    {
      f32x16 A5;
      #pragma unroll
      for (int i = 0; i < 16; ++i) A5[i] = 0.f;
      #pragma unroll
      for (int kk = 0; kk < 8; ++kk) {
        const short8 w = *(const short8*)(W + 131072 + ((l31 * 256 + kk * 32 + hi * 16) ^ swl));
        A5 = __builtin_amdgcn_mfma_f32_32x32x16_bf16(
            w, __builtin_bit_cast(short8, bcur[kk]), A5, 0, 0, 0);
      }
      // mean over the 8 neighbors = lanes 8q..8q+7 (lo half)
      float r0 = A5[0], r1 = A5[1], r2 = A5[2], r3 = A5[3];
      #pragma unroll
      for (int d = 1; d < 8; d <<= 1) {
        r0 += __shfl_xor(r0, d, 64);
        r1 += __shfl_xor(r1, d, 64);
        r2 += __shfl_xor(r2, d, 64);
        r3 += __shfl_xor(r3, d, 64);
      }
      if (hi == 0 && (l31 & 7) == 0) {
        const f32x4 b5v = *(const f32x4*)b5;
        f32x4 o;
        o.x = __builtin_fmaf(0.125f, r0, b5v.x);
        o.y = __builtin_fmaf(0.125f, r1, b5v.y);
        o.z = __builtin_fmaf(0.125f, r2, b5v.z);
        o.w = __builtin_fmaf(0.125f, r3, b5v.w);
        *(f32x4*)(out + (wg * 4 + (l31 >> 3)) * 4) = o;
      }
    }
  }
}

extern "C" void kernel_launch(void* const* d_in, const int* in_sizes, int n_in,
                              void* d_out, int out_size, void* d_ws, size_t ws_size,
                              hipStream_t stream) {
  const float* qp      = (const float*)d_in[0];
  const float* pts     = (const float*)d_in[1];
  const float* freqs   = (const float*)d_in[2];
  const float* W1      = (const float*)d_in[3];
  const float* b1      = (const float*)d_in[4];
  const float* W2      = (const float*)d_in[5];
  const float* b2      = (const float*)d_in[6];
  const float* W3      = (const float*)d_in[7];
  const float* b3      = (const float*)d_in[8];
  const float* W4      = (const float*)d_in[9];
  const float* b4      = (const float*)d_in[10];
  const float* W5      = (const float*)d_in[11];
  const float* b5      = (const float*)d_in[12];
  const int*   mapping = (const int*)d_in[13];
  u16* ws = (u16*)d_ws;
  float* out = (float*)d_out;

  prep_weights<<<dim3(274), dim3(256), 0, stream>>>(
      W1, b1, W2, W3, W4, W5, b2, b3, b4, ws);
  // 512 blocks x 16 waves x 4 iters x 32 samples = 1,048,576 rows
  domino_main<<<dim3(512), dim3(1024), 0, stream>>>(
      qp, pts, freqs, b5, mapping, ws, out);
}